// Round 6
// baseline (171.214 us; speedup 1.0000x reference)
//
#include <hip/hip_runtime.h>
#include <math.h>

// Problem constants from the reference
constexpr int BS = 64, NC = 16, TS = 200, D = 64;
constexpr int SLAB   = TS * D;        // 12800 contiguous floats per (b,c) cell
constexpr int NSLABS = BS * NC;       // 1024 output cells
constexpr int BLOCK  = 640;           // 10 waves; 3200/640 = 5 -> NO tail
constexpr int NV4    = SLAB / 4;      // 3200 float4 per slab
constexpr int ROUNDS = NV4 / BLOCK;   // 5 full rounds, exact
// 200 * (0.5 * 64 * log(2*pi)) — total normalization constant per (b,c)
constexpr float LOGNORM_TOTAL = 11762.413225f;

static_assert(ROUNDS * BLOCK == NV4, "tailless decomposition");

// Native clang vector type: works with __builtin_nontemporal_load/store
typedef float vfloat4 __attribute__((ext_vector_type(4)));

__device__ __forceinline__ void body(const vfloat4& s_in, const vfloat4& m,
                                     const vfloat4& e, vfloat4& o,
                                     float& accE, float& accL)
{
    float sx = s_in.x + 1e-5f, sy = s_in.y + 1e-5f,
          sz = s_in.z + 1e-5f, sw = s_in.w + 1e-5f;
    o.x = fmaf(sx, e.x, m.x);
    o.y = fmaf(sy, e.y, m.y);
    o.z = fmaf(sz, e.z, m.z);
    o.w = fmaf(sw, e.w, m.w);
    // z = (xi-mu)/s == eps up to rounding noise (<<< tolerance)
    accE = fmaf(e.x, e.x, accE);
    accE = fmaf(e.y, e.y, accE);
    accE = fmaf(e.z, e.z, accE);
    accE = fmaf(e.w, e.w, accE);
    accL += __logf(sx) + __logf(sy) + __logf(sz) + __logf(sw);
}

__global__ __launch_bounds__(BLOCK)
void Calc_Xi_And_LogLikelihood_71777493451127_kernel(
    const float* __restrict__ mu,
    const float* __restrict__ sigma,
    const float* __restrict__ eps,
    float* __restrict__ xi,
    float* __restrict__ ll)
{
    const int slab = blockIdx.x;                 // one block per (b,c)
    const size_t base = (size_t)slab * SLAB;

    const vfloat4* __restrict__ mu4 = (const vfloat4*)(mu    + base);
    const vfloat4* __restrict__ sg4 = (const vfloat4*)(sigma + base);
    const vfloat4* __restrict__ ep4 = (const vfloat4*)(eps   + base);
    vfloat4* __restrict__ xi4       = (vfloat4*)(xi + base);

    const int tid = threadIdx.x;

    // ---- Front-load ALL reads (15 x dwordx4 per thread): max MLP, grouped
    // by array for DRAM row locality; read phase fully separated from the
    // write phase (fewer R/W turnarounds). No tail: 640*5 == 3200.
    vfloat4 S[ROUNDS], M[ROUNDS], E[ROUNDS];

    #pragma unroll
    for (int j = 0; j < ROUNDS; ++j)
        S[j] = __builtin_nontemporal_load(&sg4[tid + j * BLOCK]);
    #pragma unroll
    for (int j = 0; j < ROUNDS; ++j)
        M[j] = __builtin_nontemporal_load(&mu4[tid + j * BLOCK]);
    #pragma unroll
    for (int j = 0; j < ROUNDS; ++j)
        E[j] = __builtin_nontemporal_load(&ep4[tid + j * BLOCK]);

    // ---- Compute + store phase
    float accE = 0.0f;   // sum of eps^2
    float accL = 0.0f;   // sum of log(s)

    #pragma unroll
    for (int j = 0; j < ROUNDS; ++j) {
        vfloat4 o;
        body(S[j], M[j], E[j], o, accE, accL);
        __builtin_nontemporal_store(o, &xi4[tid + j * BLOCK]);
    }

    float acc = -0.5f * accE - accL;

    // Wave-64 shuffle reduction, then cross-wave via LDS (10 waves/block)
    #pragma unroll
    for (int off = 32; off > 0; off >>= 1)
        acc += __shfl_down(acc, off, 64);

    __shared__ float wsum[BLOCK / 64];
    const int lane = tid & 63;
    const int wid  = tid >> 6;
    if (lane == 0) wsum[wid] = acc;
    __syncthreads();

    if (tid == 0) {
        float t = 0.0f;
        #pragma unroll
        for (int w = 0; w < BLOCK / 64; ++w) t += wsum[w];
        ll[slab] = t - LOGNORM_TOTAL;
    }
}

extern "C" void kernel_launch(void* const* d_in, const int* in_sizes, int n_in,
                              void* d_out, int out_size, void* d_ws, size_t ws_size,
                              hipStream_t stream) {
    const float* mu    = (const float*)d_in[0];
    const float* sigma = (const float*)d_in[1];
    const float* eps   = (const float*)d_in[2];

    float* xi = (float*)d_out;                         // first output, 13,107,200 floats
    float* ll = (float*)d_out + (size_t)NSLABS * SLAB; // second output, 1024 floats

    Calc_Xi_And_LogLikelihood_71777493451127_kernel<<<NSLABS, BLOCK, 0, stream>>>(
        mu, sigma, eps, xi, ll);
}